// Round 11
// baseline (461.729 us; speedup 1.0000x reference)
//
#include <hip/hip_runtime.h>
#include <hip/hip_bf16.h>
#include <hip/hip_fp16.h>

// Storage-dtype-templated load: DT=0 bf16, DT=1 fp16, DT=2 f32.
template <int DT>
__device__ __forceinline__ float ldT(const void* p, long i) {
  if (DT == 0) {
    unsigned int a = ((unsigned int)((const unsigned short*)p)[i]) << 16;
    union { unsigned int u; float f; } c; c.u = a; return c.f;
  } else if (DT == 1) {
    return __half2float(((const __half*)p)[i]);
  } else {
    return ((const float*)p)[i];
  }
}
template <int DT>
__device__ __forceinline__ bool msknzT(const void* p, long i) {
  if (DT < 2) return ((const unsigned short*)p)[i] != 0;  // 0.0 encodes as 0x0000
  return ((const float*)p)[i] != 0.f;
}
__device__ __forceinline__ float wred64(float v) {
#pragma unroll
  for (int off = 1; off < 64; off <<= 1) v += __shfl_xor(v, off, 64);
  return v;
}

// ---------------- init: dtype classify + batch ranges (one launch) ----------------
__global__ void ct67_init(const unsigned short* x0u, const int* b0, const int* b1,
                          const int* b2, int* ranges, int* flags) {
  int t = threadIdx.x;
  if (t == 63) {
    float vals[32];
    for (int i = 0; i < 32; i++) {
      union { unsigned int u; float f; } c;
      c.u = ((unsigned int)x0u[i]) << 16;
      vals[i] = c.f;
    }
    float mean = 0.f;
    for (int i = 0; i < 32; i++) mean += vals[i];
    mean /= 32.f;
    float var = 0.f;
    for (int i = 0; i < 32; i++) var += (vals[i] - mean) * (vals[i] - mean);
    var /= 32.f;
    int dt;
    if (var < 1e-6f) dt = 1;       // fp16 stored
    else if (var < 1e3f) dt = 0;   // bf16 stored
    else dt = 2;                   // f32 stored
    flags[0] = dt;
  }
  if (t < 24) {
    int d = t / 8, b = t % 8;
    const int* bel = (d == 0) ? b0 : ((d == 1) ? b1 : b2);
    int N = (d == 1) ? 3072 : 1536;
    int lo = 0, hi = N;
    while (lo < hi) { int m = (lo + hi) / 2; if (bel[m] < b) lo = m + 1; else hi = m; }
    int st = lo; hi = N;
    while (lo < hi) { int m = (lo + hi) / 2; if (bel[m] < b + 1) lo = m + 1; else hi = m; }
    ranges[t * 2] = st;
    ranges[t * 2 + 1] = lo;
  }
}

// ---------------- mask transpose: b01 and b12 in one flattened grid ----------------
__global__ void ct67_tpose(const void* b01, const void* b12, void* b01T, void* b12T,
                           const int* dtp) {
  __shared__ unsigned int tile[32][33];
  int dt = dtp[0];
  int id = blockIdx.x;
  int tx = threadIdx.x % 32, ty = threadIdx.x / 32;
  const void* in; void* out; int R, C, tilex, tiley;
  if (id < 4608) { in = b01; out = b01T; R = 1536; C = 3072; tilex = id % 96; tiley = id / 96; }
  else { id -= 4608; in = b12; out = b12T; R = 3072; C = 1536; tilex = id % 48; tiley = id / 48; }
  int r0 = tiley * 32, c0 = tilex * 32;
  if (dt < 2) {
    const unsigned short* ip = (const unsigned short*)in;
    unsigned short* op = (unsigned short*)out;
    for (int k = 0; k < 4; k++) tile[ty + k * 8][tx] = ip[(long)(r0 + ty + k * 8) * C + c0 + tx];
    __syncthreads();
    for (int k = 0; k < 4; k++)
      op[(long)(c0 + ty + k * 8) * R + r0 + tx] = (unsigned short)tile[tx][ty + k * 8];
  } else {
    const unsigned int* ip = (const unsigned int*)in;
    unsigned int* op = (unsigned int*)out;
    for (int k = 0; k < 4; k++) tile[ty + k * 8][tx] = ip[(long)(r0 + ty + k * 8) * C + c0 + tx];
    __syncthreads();
    for (int k = 0; k < 4; k++)
      op[(long)(c0 + ty + k * 8) * R + r0 + tx] = tile[tx][ty + k * 8];
  }
}

// interaction decode
__device__ __forceinline__ void ct67_itab(int bi, int& i, int& t) {
  const int toff[8] = {0, 1536, 4608, 6144, 9216, 10752, 13824, 15360};
  i = 0;
  while (bi >= toff[i + 1]) i++;
  t = bi - toff[i];
}

// ---------------- ELL hit-list build (layer-invariant) ----------------
template <int DT>
__device__ void ellb_body(const void* adj00, const void* b01, const void* adj11,
                          const void* b12, const void* adj22,
                          const void* b01T, const void* b12T, int tpok,
                          const int* bel0, const int* bel1, const int* bel2,
                          const int* ranges, int* ell, int* nnz) {
  const int sdv[7] = {0, 0, 1, 1, 1, 2, 2};
  const int tdv[7] = {0, 1, 0, 1, 2, 1, 2};
  int bi = blockIdx.x;
  int i, t;
  ct67_itab(bi, i, t);
  int lane = threadIdx.x;
  const void* mp; long mts, mss;
  switch (i) {
    case 0: mp = adj00; mts = 1536; mss = 1; break;
    case 1: if (tpok) { mp = b01T; mts = 1536; mss = 1; }
            else      { mp = b01;  mts = 1;    mss = 3072; } break;
    case 2: mp = b01; mts = 3072; mss = 1; break;
    case 3: mp = adj11; mts = 3072; mss = 1; break;
    case 4: if (tpok) { mp = b12T; mts = 3072; mss = 1; }
            else      { mp = b12;  mts = 1;    mss = 1536; } break;
    case 5: mp = b12; mts = 1536; mss = 1; break;
    default: mp = adj22; mts = 1536; mss = 1; break;
  }
  const int* belt = (tdv[i] == 0) ? bel0 : ((tdv[i] == 1) ? bel1 : bel2);
  int b = belt[t];
  if (b < 0) b = 0;
  if (b > 7) b = 7;
  const int* rng = ranges + sdv[i] * 16;
  int s0 = rng[b * 2], s1 = rng[b * 2 + 1];
  int base = 0;
  for (int s = s0; s < s1; s += 64) {
    int ss = s + lane;
    bool pred = false;
    if (ss < s1) pred = msknzT<DT>(mp, (long)t * mts + (long)ss * mss);
    unsigned long long bal = __ballot(pred);
    int pos = __popcll(bal & ((1ull << lane) - 1ull));
    if (pred && base + pos < 128) ell[(long)bi * 128 + base + pos] = ss;
    base += __popcll(bal);
  }
  if (lane == 0) nnz[bi] = base;
}
__global__ void ct67_ellb(const void* adj00, const void* b01, const void* adj11,
                          const void* b12, const void* adj22,
                          const void* b01T, const void* b12T, int tpok,
                          const int* bel0, const int* bel1, const int* bel2,
                          const int* ranges, int* ell, int* nnz, const int* dtp) {
  int dt = dtp[0];
  if (dt == 0)
    ellb_body<0>(adj00,b01,adj11,b12,adj22,b01T,b12T,tpok,bel0,bel1,bel2,ranges,ell,nnz);
  else if (dt == 1)
    ellb_body<1>(adj00,b01,adj11,b12,adj22,b01T,b12T,tpok,bel0,bel1,bel2,ranges,ell,nnz);
  else
    ellb_body<2>(adj00,b01,adj11,b12,adj22,b01T,b12T,tpok,bel0,bel1,bel2,ranges,ell,nnz);
}

// ---------------- embed (merged dims) ----------------
template <int DT>
__device__ void embed_body(const void* x0, const void* pe0, const void* wf0, const void* bf0,
                           const void* wp0, const void* x1, const void* pe1, const void* wf1,
                           const void* bf1, const void* wp1, const void* x2, const void* pe2,
                           const void* wf2, const void* bf2, const void* wp2, float* hout) {
  int j = threadIdx.x % 64;
  int row = blockIdx.x * 4 + threadIdx.x / 64;
  int d = (row < 1536) ? 0 : ((row < 4608) ? 1 : 2);
  int r = row - ((d == 0) ? 0 : ((d == 1) ? 1536 : 4608));
  const void* x  = (d == 0) ? x0  : ((d == 1) ? x1  : x2);
  const void* pe = (d == 0) ? pe0 : ((d == 1) ? pe1 : pe2);
  const void* wf = (d == 0) ? wf0 : ((d == 1) ? wf1 : wf2);
  const void* bf = (d == 0) ? bf0 : ((d == 1) ? bf1 : bf2);
  const void* wp = (d == 0) ? wp0 : ((d == 1) ? wp1 : wp2);
  float acc = ldT<DT>(bf, j);
#pragma unroll 8
  for (int f = 0; f < 32; f++) acc += ldT<DT>(x, (long)r * 32 + f) * ldT<DT>(wf, f * 64 + j);
#pragma unroll 8
  for (int p = 0; p < 16; p++) acc += ldT<DT>(pe, (long)r * 16 + p) * ldT<DT>(wp, p * 64 + j);
  hout[(long)row * 64 + j] = acc;
}
__global__ void ct67_embed(const void* x0, const void* pe0, const void* wf0, const void* bf0,
                           const void* wp0, const void* x1, const void* pe1, const void* wf1,
                           const void* bf1, const void* wp1, const void* x2, const void* pe2,
                           const void* wf2, const void* bf2, const void* wp2, float* hout,
                           const int* dtp) {
  int dt = dtp[0];
  if (dt == 0)      embed_body<0>(x0,pe0,wf0,bf0,wp0,x1,pe1,wf1,bf1,wp1,x2,pe2,wf2,bf2,wp2,hout);
  else if (dt == 1) embed_body<1>(x0,pe0,wf0,bf0,wp0,x1,pe1,wf1,bf1,wp1,x2,pe2,wf2,bf2,wp2,hout);
  else              embed_body<2>(x0,pe0,wf0,bf0,wp0,x1,pe1,wf1,bf1,wp1,x2,pe2,wf2,bf2,wp2,hout);
}

// ---------------- qkv: 8 rows/block, W decoded once into f32 LDS ----------------
template <int DT>
__device__ void qkv_body(const float* h, const void* Wq, const void* bq, const void* Wk,
                         const void* bk, const void* Wv, const void* bv,
                         float* qd, float* kd, float* vd, int l) {
  const int segend[21] = {1536, 3072, 4608, 7680, 9216, 10752, 12288, 15360, 18432,
                          21504, 24576, 27648, 29184, 32256, 35328, 38400, 39936,
                          41472, 43008, 44544, 46080};
  const int segsrc[21] = {0, 0, 0, 1, 0, 0, 0, 1, 1, 1, 1, 1, 2, 1, 1, 1, 2, 2, 2, 2, 2};
  const int segdst[21] = {0, 0, 0, 1536, 1536, 1536, 4608, 3072, 3072, 6144, 6144, 6144,
                          9216, 9216, 9216, 10752, 12288, 12288, 13824, 13824, 13824};
  const int rowoff[3] = {0, 1536, 4608};
  __shared__ float sW[4096];
  __shared__ float sh[8][64];
  int tid = threadIdx.x;
  int j = tid % 64;
  int rg = tid / 64;
  int gbase = blockIdx.x * 8;  // segment boundaries are multiples of 8
  int seg = 0;
  while (gbase >= segend[seg]) seg++;
  int segstart = (seg == 0) ? 0 : segend[seg - 1];
  int i = seg / 3, role = seg - i * 3;
  const void* W = (role == 0) ? Wq : (role == 1) ? Wk : Wv;
  const void* bb = (role == 0) ? bq : (role == 1) ? bk : bv;
  long wbase = (long)(l * 7 + i) * 4096;
#pragma unroll
  for (int kkk = 0; kkk < 8; kkk++) {
    int idx = tid + kkk * 512;
    sW[idx] = ldT<DT>(W, wbase + idx);
  }
  int r = gbase - segstart + rg;
  int hrow = rowoff[segsrc[seg]] + r;
  sh[rg][j] = h[(long)hrow * 64 + j];
  __syncthreads();
  float acc = ldT<DT>(bb, (long)(l * 7 + i) * 64 + j);
#pragma unroll 8
  for (int kk = 0; kk < 64; kk++) acc += sh[rg][kk] * sW[kk * 64 + j];
  float* dst = ((role == 0) ? qd : (role == 1) ? kd : vd) + (long)(segdst[seg] + r) * 64;
  dst[j] = acc;
}
__global__ void ct67_qkv(const float* h, const void* Wq, const void* bq, const void* Wk,
                         const void* bk, const void* Wv, const void* bv,
                         float* qd, float* kd, float* vd, int l, const int* dtp) {
  int dt = dtp[0];
  if (dt == 0)      qkv_body<0>(h, Wq, bq, Wk, bk, Wv, bv, qd, kd, vd, l);
  else if (dt == 1) qkv_body<1>(h, Wq, bq, Wk, bk, Wv, bv, qd, kd, vd, l);
  else              qkv_body<2>(h, Wq, bq, Wk, bk, Wv, bv, qd, kd, vd, l);
}

// ---------------- fused masked attention + output projection (ELL hit lists) ----
template <int DT>
__device__ void attn_body(const float* qb, const float* kb, const float* vb,
                          const void* Wo, const void* bo,
                          const void* adj00, const void* b01, const void* adj11,
                          const void* b12, const void* adj22,
                          const int* bel0, const int* bel1, const int* bel2,
                          const int* ranges, const int* ell, const int* nnz, int ellok,
                          float* obuf, int l) {
  const int koff[7] = {0, 1536, 3072, 6144, 9216, 12288, 13824};
  const int sdv[7] = {0, 0, 1, 1, 1, 2, 2};
  const int tdv[7] = {0, 1, 0, 1, 2, 1, 2};
  __shared__ float sm[64], sl[64], so8[64][9], sO[64];
  int bi = blockIdx.x;
  int i, t;
  ct67_itab(bi, i, t);
  int lane = threadIdx.x;
  int hh = lane / 8, jj = lane % 8;
  const float4* qp = (const float4*)(qb + (long)bi * 64 + hh * 8);
  float4 q0 = qp[0], q1 = qp[1];
  const float* kbase = kb + (long)koff[i] * 64 + hh * 8;
  const float* vbase = vb + (long)koff[i] * 64 + hh * 8;
  float mr = -1e30f, lr = 0.f, o[8];
  for (int d = 0; d < 8; d++) o[d] = 0.f;
  int n = ellok ? nnz[bi] : 129;
  if (n <= 128) {
    const int* hl = ell + (long)bi * 128;
    for (int hidx = jj; hidx < n; hidx += 8) {
      int s = hl[hidx];
      const float4* kp = (const float4*)(kbase + (long)s * 64);
      float4 k0 = kp[0], k1 = kp[1];
      float sc = q0.x * k0.x + q0.y * k0.y + q0.z * k0.z + q0.w * k0.w +
                 q1.x * k1.x + q1.y * k1.y + q1.z * k1.z + q1.w * k1.w;
      sc *= 0.35355339059327373f;
      float nm = fmaxf(mr, sc);
      float fo = expf(mr - nm);
      float wv = expf(sc - nm);
      lr = lr * fo + wv;
      const float4* vp = (const float4*)(vbase + (long)s * 64);
      float4 v0 = vp[0], v1 = vp[1];
      o[0] = o[0] * fo + wv * v0.x; o[1] = o[1] * fo + wv * v0.y;
      o[2] = o[2] * fo + wv * v0.z; o[3] = o[3] * fo + wv * v0.w;
      o[4] = o[4] * fo + wv * v1.x; o[5] = o[5] * fo + wv * v1.y;
      o[6] = o[6] * fo + wv * v1.z; o[7] = o[7] * fo + wv * v1.w;
      mr = nm;
    }
  } else {  // fallback: in-loop mask scan
    const void* mp; long mts, mss;
    switch (i) {
      case 0: mp = adj00; mts = 1536; mss = 1; break;
      case 1: mp = b01;   mts = 1;    mss = 3072; break;
      case 2: mp = b01;   mts = 3072; mss = 1; break;
      case 3: mp = adj11; mts = 3072; mss = 1; break;
      case 4: mp = b12;   mts = 1;    mss = 1536; break;
      case 5: mp = b12;   mts = 1536; mss = 1; break;
      default: mp = adj22; mts = 1536; mss = 1; break;
    }
    const int* belt = (tdv[i] == 0) ? bel0 : ((tdv[i] == 1) ? bel1 : bel2);
    int b = belt[t];
    if (b < 0) b = 0;
    if (b > 7) b = 7;
    const int* rng = ranges + sdv[i] * 16;
    int s0 = rng[b * 2], s1 = rng[b * 2 + 1];
    for (int s = s0 + jj; s < s1; s += 8) {
      if (msknzT<DT>(mp, (long)t * mts + (long)s * mss)) {
        const float4* kp = (const float4*)(kbase + (long)s * 64);
        float4 k0 = kp[0], k1 = kp[1];
        float sc = q0.x * k0.x + q0.y * k0.y + q0.z * k0.z + q0.w * k0.w +
                   q1.x * k1.x + q1.y * k1.y + q1.z * k1.z + q1.w * k1.w;
        sc *= 0.35355339059327373f;
        float nm = fmaxf(mr, sc);
        float fo = expf(mr - nm);
        float wv = expf(sc - nm);
        lr = lr * fo + wv;
        const float4* vp = (const float4*)(vbase + (long)s * 64);
        float4 v0 = vp[0], v1 = vp[1];
        o[0] = o[0] * fo + wv * v0.x; o[1] = o[1] * fo + wv * v0.y;
        o[2] = o[2] * fo + wv * v0.z; o[3] = o[3] * fo + wv * v0.w;
        o[4] = o[4] * fo + wv * v1.x; o[5] = o[5] * fo + wv * v1.y;
        o[6] = o[6] * fo + wv * v1.z; o[7] = o[7] * fo + wv * v1.w;
        mr = nm;
      }
    }
  }
  sm[lane] = mr;
  sl[lane] = lr;
  for (int d = 0; d < 8; d++) so8[lane][d] = o[d];
  __syncthreads();
  if (jj == 0) {
    float M = -1e30f, L = 0.f, O[8];
    for (int d = 0; d < 8; d++) O[d] = 0.f;
    for (int p = 0; p < 8; p++) {
      int src = hh * 8 + p;
      float m2 = sm[src], l2 = sl[src];
      float nm = fmaxf(M, m2);
      float f1 = expf(M - nm), f2 = expf(m2 - nm);
      L = L * f1 + l2 * f2;
      for (int d = 0; d < 8; d++) O[d] = O[d] * f1 + so8[src][d] * f2;
      M = nm;
    }
    for (int d = 0; d < 8; d++) sO[hh * 8 + d] = (L > 0.f) ? (O[d] / L) : 0.f;
  }
  __syncthreads();
  long wobase = (long)(l * 7 + i) * 4096;
  float acc = ldT<DT>(bo, (long)(l * 7 + i) * 64 + lane);
#pragma unroll 8
  for (int kk = 0; kk < 64; kk++) acc += sO[kk] * ldT<DT>(Wo, wobase + kk * 64 + lane);
  obuf[(long)bi * 64 + lane] = acc;
}
__global__ void CellularTransformer_67345087201410_kernel(
    const float* qb, const float* kb, const float* vb, const void* Wo, const void* bo,
    const void* adj00, const void* b01, const void* adj11, const void* b12,
    const void* adj22, const int* bel0, const int* bel1, const int* bel2,
    const int* ranges, const int* ell, const int* nnz, int ellok,
    float* obuf, int l, const int* dtp) {
  int dt = dtp[0];
  if (dt == 0)
    attn_body<0>(qb,kb,vb,Wo,bo,adj00,b01,adj11,b12,adj22,bel0,bel1,bel2,ranges,ell,nnz,ellok,obuf,l);
  else if (dt == 1)
    attn_body<1>(qb,kb,vb,Wo,bo,adj00,b01,adj11,b12,adj22,bel0,bel1,bel2,ranges,ell,nnz,ellok,obuf,l);
  else
    attn_body<2>(qb,kb,vb,Wo,bo,adj00,b01,adj11,b12,adj22,bel0,bel1,bel2,ranges,ell,nnz,ellok,obuf,l);
}

// ---------------- fused FFN: LN1 -> FF1(relu) -> FF2 -> LN2, all in LDS ----------
template <int DT>
__device__ void ffn_body(const float* h, const float* obuf, float* hout,
                         const void* W1, const void* b1, const void* W2, const void* b2,
                         const void* g1, const void* be1, const void* g2, const void* be2,
                         int l) {
  __shared__ float sh[64];     // hn (LN1 output)
  __shared__ float sf[256];    // relu(hn@W1+b1)
  __shared__ float sp[4][64];  // ff2 partials
  int row = blockIdx.x;
  int tid = threadIdx.x;
  int d = (row < 1536) ? 0 : ((row < 4608) ? 1 : 2);
  long gb = (long)(l * 3 + d) * 64;
  // Phase A: wave 0 computes LN1(h + attn outputs)
  if (tid < 64) {
    int j = tid;
    long idx = (long)row * 64 + j;
    float x = h[idx];
    if (d == 0) {
      int r = row;
      x += obuf[(long)r * 64 + j] + obuf[(long)(4608 + r) * 64 + j];
    } else if (d == 1) {
      int r = row - 1536;
      x += obuf[(long)(1536 + r) * 64 + j] + obuf[(long)(6144 + r) * 64 + j] +
           obuf[(long)(10752 + r) * 64 + j];
    } else {
      int r = row - 4608;
      x += obuf[(long)(9216 + r) * 64 + j] + obuf[(long)(13824 + r) * 64 + j];
    }
    float mu = wred64(x) * 0.015625f;
    float dx = x - mu;
    float var = wred64(dx * dx) * 0.015625f;
    sh[j] = dx * rsqrtf(var + 1e-5f) * ldT<DT>(g1, gb + j) + ldT<DT>(be1, gb + j);
  }
  __syncthreads();
  // Phase B: 256 threads compute ff cols
  long wb1 = (long)(l * 3 + d) * 16384;
  float acc = ldT<DT>(b1, (long)(l * 3 + d) * 256 + tid);
#pragma unroll 8
  for (int kk = 0; kk < 64; kk++) acc += sh[kk] * ldT<DT>(W1, wb1 + kk * 256 + tid);
  sf[tid] = fmaxf(acc, 0.f);
  __syncthreads();
  // Phase C: ff @ W2 with 4 k-partials per output col
  int p = tid >> 6, j = tid & 63;
  long wb2 = (long)(l * 3 + d) * 16384;
  float a2 = 0.f;
  int k0 = p * 64;
#pragma unroll 8
  for (int kk = 0; kk < 64; kk++) a2 += sf[k0 + kk] * ldT<DT>(W2, wb2 + (long)(k0 + kk) * 64 + j);
  sp[p][j] = a2;
  __syncthreads();
  // Phase D: wave 0 reduces partials, adds residual, LN2, writes h
  if (tid < 64) {
    float x = sh[tid] + ldT<DT>(b2, gb + tid) +
              sp[0][tid] + sp[1][tid] + sp[2][tid] + sp[3][tid];
    float mu = wred64(x) * 0.015625f;
    float dx = x - mu;
    float var = wred64(dx * dx) * 0.015625f;
    hout[(long)row * 64 + tid] =
        dx * rsqrtf(var + 1e-5f) * ldT<DT>(g2, gb + tid) + ldT<DT>(be2, gb + tid);
  }
}
__global__ void ct67_ffn(const float* h, const float* obuf, float* hout,
                         const void* W1, const void* b1, const void* W2, const void* b2,
                         const void* g1, const void* be1, const void* g2, const void* be2,
                         int l, const int* dtp) {
  int dt = dtp[0];
  if (dt == 0)      ffn_body<0>(h, obuf, hout, W1, b1, W2, b2, g1, be1, g2, be2, l);
  else if (dt == 1) ffn_body<1>(h, obuf, hout, W1, b1, W2, b2, g1, be1, g2, be2, l);
  else              ffn_body<2>(h, obuf, hout, W1, b1, W2, b2, g1, be1, g2, be2, l);
}

// ---------------- pooling: one kernel, 8 blocks x 256 threads ----------------
__global__ void ct67_pool(const float* h, const int* ranges, float* pooled) {
  __shared__ float sp[4][64];
  int b = blockIdx.x;
  int tid = threadIdx.x;
  int p = tid >> 6, j = tid & 63;
  float s = 0.f;
  for (int d = 0; d < 3; d++) {
    int st = ranges[(d * 8 + b) * 2], en = ranges[(d * 8 + b) * 2 + 1];
    int ro = (d == 0) ? 0 : ((d == 1) ? 1536 : 4608);
    for (int r = st + p; r < en; r += 4) s += h[(long)(ro + r) * 64 + j];
  }
  sp[p][j] = s;
  __syncthreads();
  if (tid < 64) {
    float t = sp[0][tid] + sp[1][tid] + sp[2][tid] + sp[3][tid];
    int cnt = 0;
    for (int d = 0; d < 3; d++)
      cnt += ranges[(d * 8 + b) * 2 + 1] - ranges[(d * 8 + b) * 2];
    pooled[b * 64 + tid] = (cnt > 0) ? (t / (float)cnt) : 0.f;
  }
}

// ---------------- head MLP ----------------
template <int DT>
__device__ void mlp_body(const float* pooled, const void* Wh1, const void* bh1,
                         const void* Wh2, const void* bh2, const void* Wh3,
                         const void* bh3, float* out) {
  __shared__ float y1[8][64];
  __shared__ float y2[8][64];
  int tid = threadIdx.x;
  int b = tid / 64, j = tid % 64;
  float acc = ldT<DT>(bh1, j);
  for (int kk = 0; kk < 64; kk++) acc += pooled[b * 64 + kk] * ldT<DT>(Wh1, kk * 64 + j);
  y1[b][j] = fmaxf(acc, 0.f);
  __syncthreads();
  acc = ldT<DT>(bh2, j);
  for (int kk = 0; kk < 64; kk++) acc += y1[b][kk] * ldT<DT>(Wh2, kk * 64 + j);
  y2[b][j] = fmaxf(acc, 0.f);
  __syncthreads();
  if (j < 10) {
    float o = ldT<DT>(bh3, j);
    for (int kk = 0; kk < 64; kk++) o += y2[b][kk] * ldT<DT>(Wh3, kk * 10 + j);
    out[b * 10 + j] = o;
  }
}
__global__ void ct67_mlp(const float* pooled, const void* Wh1, const void* bh1,
                         const void* Wh2, const void* bh2, const void* Wh3,
                         const void* bh3, float* out, const int* dtp) {
  int dt = dtp[0];
  if (dt == 0)      mlp_body<0>(pooled, Wh1, bh1, Wh2, bh2, Wh3, bh3, out);
  else if (dt == 1) mlp_body<1>(pooled, Wh1, bh1, Wh2, bh2, Wh3, bh3, out);
  else              mlp_body<2>(pooled, Wh1, bh1, Wh2, bh2, Wh3, bh3, out);
}

extern "C" void kernel_launch(void* const* d_in, const int* in_sizes, int n_in,
                              void* d_out, int out_size, void* d_ws, size_t ws_size,
                              hipStream_t stream) {
  (void)in_sizes; (void)n_in; (void)out_size;
  const void* x0 = d_in[0];  const void* pe0 = d_in[1];  const int* bel0 = (const int*)d_in[2];
  const void* x1 = d_in[3];  const void* pe1 = d_in[4];  const int* bel1 = (const int*)d_in[5];
  const void* x2 = d_in[6];  const void* pe2 = d_in[7];  const int* bel2 = (const int*)d_in[8];
  const void* adj00 = d_in[9];  const void* adj11 = d_in[10]; const void* adj22 = d_in[11];
  const void* b01 = d_in[12];   const void* b12 = d_in[13];
  const void* Wf0 = d_in[14]; const void* bf0 = d_in[15]; const void* Wp0 = d_in[16];
  const void* Wf1 = d_in[17]; const void* bf1 = d_in[18]; const void* Wp1 = d_in[19];
  const void* Wf2 = d_in[20]; const void* bf2 = d_in[21]; const void* Wp2 = d_in[22];
  const void* Wq = d_in[23]; const void* bq = d_in[24];
  const void* Wk = d_in[25]; const void* bk = d_in[26];
  const void* Wv = d_in[27]; const void* bv = d_in[28];
  const void* Wo = d_in[29]; const void* bo = d_in[30];
  const void* g1 = d_in[31]; const void* be1 = d_in[32];
  const void* g2 = d_in[33]; const void* be2 = d_in[34];
  const void* Wff1 = d_in[35]; const void* bff1 = d_in[36];
  const void* Wff2 = d_in[37]; const void* bff2 = d_in[38];
  const void* Wh1 = d_in[39]; const void* bh1 = d_in[40];
  const void* Wh2 = d_in[41]; const void* bh2 = d_in[42];
  const void* Wh3 = d_in[43]; const void* bh3 = d_in[44];

  char* w = (char*)d_ws;
  float* hbuf   = (float*)(w + 0);          // 6144*64*4   = 1572864
  float* obuf   = (float*)(w + 1572864);    // 15360*64*4  = 3932160 -> 5505024
  float* qb     = (float*)(w + 5505024);    // -> 9437184
  float* kb     = (float*)(w + 9437184);    // -> 13369344
  float* vb     = (float*)(w + 13369344);   // -> 17301504
  float* pooled = (float*)(w + 17301504);   // 2048        -> 17303552
  int* ranges   = (int*)(w + 17303552);     // 192         -> 17303744
  int* flags    = (int*)(w + 17303744);     // 64          -> 17303808
  int* ell      = (int*)(w + 17303808);     // 15360*128*4 -> 25168128
  int* nnz      = (int*)(w + 25168128);     // 61440       -> 25229568
  void* b01T    = (void*)(w + 25229568);    // 3072*1536*4 -> 44103936
  void* b12T    = (void*)(w + 44103936);    // -> 62978304
  int ellok = (ws_size >= (size_t)25229568) ? 1 : 0;
  int tpok  = (ws_size >= (size_t)62978304) ? 1 : 0;

  ct67_init<<<1, 64, 0, stream>>>((const unsigned short*)x0, bel0, bel1, bel2, ranges, flags);
  if (tpok)
    ct67_tpose<<<9216, 256, 0, stream>>>(b01, b12, b01T, b12T, flags);
  if (ellok)
    ct67_ellb<<<15360, 64, 0, stream>>>(adj00, b01, adj11, b12, adj22, b01T, b12T, tpok,
                                        bel0, bel1, bel2, ranges, ell, nnz, flags);
  ct67_embed<<<1536, 256, 0, stream>>>(x0, pe0, Wf0, bf0, Wp0, x1, pe1, Wf1, bf1, Wp1,
                                       x2, pe2, Wf2, bf2, Wp2, hbuf, flags);
  for (int l = 0; l < 2; l++) {
    ct67_qkv<<<5760, 512, 0, stream>>>(hbuf, Wq, bq, Wk, bk, Wv, bv, qb, kb, vb, l, flags);
    CellularTransformer_67345087201410_kernel<<<15360, 64, 0, stream>>>(
        qb, kb, vb, Wo, bo, adj00, b01, adj11, b12, adj22,
        bel0, bel1, bel2, ranges, ell, nnz, ellok, obuf, l, flags);
    ct67_ffn<<<6144, 256, 0, stream>>>(hbuf, obuf, hbuf, Wff1, bff1, Wff2, bff2,
                                       g1, be1, g2, be2, l, flags);
  }
  ct67_pool<<<8, 256, 0, stream>>>(hbuf, ranges, pooled);
  ct67_mlp<<<1, 512, 0, stream>>>(pooled, Wh1, bh1, Wh2, bh2, Wh3, bh3, (float*)d_out, flags);
}

// Round 12
// 414.273 us; speedup vs baseline: 1.1146x; 1.1146x over previous
//
#include <hip/hip_runtime.h>
#include <hip/hip_bf16.h>
#include <hip/hip_fp16.h>

// Storage-dtype-templated load: DT=0 bf16, DT=1 fp16, DT=2 f32.
template <int DT>
__device__ __forceinline__ float ldT(const void* p, long i) {
  if (DT == 0) {
    unsigned int a = ((unsigned int)((const unsigned short*)p)[i]) << 16;
    union { unsigned int u; float f; } c; c.u = a; return c.f;
  } else if (DT == 1) {
    return __half2float(((const __half*)p)[i]);
  } else {
    return ((const float*)p)[i];
  }
}
template <int DT>
__device__ __forceinline__ bool msknzT(const void* p, long i) {
  if (DT < 2) return ((const unsigned short*)p)[i] != 0;  // 0.0 encodes as 0x0000
  return ((const float*)p)[i] != 0.f;
}
__device__ __forceinline__ float wred64(float v) {
#pragma unroll
  for (int off = 1; off < 64; off <<= 1) v += __shfl_xor(v, off, 64);
  return v;
}

// ---------------- init: dtype classify + batch ranges (one launch) ----------------
__global__ void ct67_init(const unsigned short* x0u, const int* b0, const int* b1,
                          const int* b2, int* ranges, int* flags) {
  int t = threadIdx.x;
  if (t == 63) {
    float vals[32];
    for (int i = 0; i < 32; i++) {
      union { unsigned int u; float f; } c;
      c.u = ((unsigned int)x0u[i]) << 16;
      vals[i] = c.f;
    }
    float mean = 0.f;
    for (int i = 0; i < 32; i++) mean += vals[i];
    mean /= 32.f;
    float var = 0.f;
    for (int i = 0; i < 32; i++) var += (vals[i] - mean) * (vals[i] - mean);
    var /= 32.f;
    int dt;
    if (var < 1e-6f) dt = 1;       // fp16 stored
    else if (var < 1e3f) dt = 0;   // bf16 stored
    else dt = 2;                   // f32 stored
    flags[0] = dt;
  }
  if (t < 24) {
    int d = t / 8, b = t % 8;
    const int* bel = (d == 0) ? b0 : ((d == 1) ? b1 : b2);
    int N = (d == 1) ? 3072 : 1536;
    int lo = 0, hi = N;
    while (lo < hi) { int m = (lo + hi) / 2; if (bel[m] < b) lo = m + 1; else hi = m; }
    int st = lo; hi = N;
    while (lo < hi) { int m = (lo + hi) / 2; if (bel[m] < b + 1) lo = m + 1; else hi = m; }
    ranges[t * 2] = st;
    ranges[t * 2 + 1] = lo;
  }
}

// ---------------- mask transpose: b01 and b12 in one flattened grid ----------------
__global__ void ct67_tpose(const void* b01, const void* b12, void* b01T, void* b12T,
                           const int* dtp) {
  __shared__ unsigned int tile[32][33];
  int dt = dtp[0];
  int id = blockIdx.x;
  int tx = threadIdx.x % 32, ty = threadIdx.x / 32;
  const void* in; void* out; int R, C, tilex, tiley;
  if (id < 4608) { in = b01; out = b01T; R = 1536; C = 3072; tilex = id % 96; tiley = id / 96; }
  else { id -= 4608; in = b12; out = b12T; R = 3072; C = 1536; tilex = id % 48; tiley = id / 48; }
  int r0 = tiley * 32, c0 = tilex * 32;
  if (dt < 2) {
    const unsigned short* ip = (const unsigned short*)in;
    unsigned short* op = (unsigned short*)out;
    for (int k = 0; k < 4; k++) tile[ty + k * 8][tx] = ip[(long)(r0 + ty + k * 8) * C + c0 + tx];
    __syncthreads();
    for (int k = 0; k < 4; k++)
      op[(long)(c0 + ty + k * 8) * R + r0 + tx] = (unsigned short)tile[tx][ty + k * 8];
  } else {
    const unsigned int* ip = (const unsigned int*)in;
    unsigned int* op = (unsigned int*)out;
    for (int k = 0; k < 4; k++) tile[ty + k * 8][tx] = ip[(long)(r0 + ty + k * 8) * C + c0 + tx];
    __syncthreads();
    for (int k = 0; k < 4; k++)
      op[(long)(c0 + ty + k * 8) * R + r0 + tx] = tile[tx][ty + k * 8];
  }
}

// interaction decode
__device__ __forceinline__ void ct67_itab(int bi, int& i, int& t) {
  const int toff[8] = {0, 1536, 4608, 6144, 9216, 10752, 13824, 15360};
  i = 0;
  while (bi >= toff[i + 1]) i++;
  t = bi - toff[i];
}

// ---------------- ELL hit-list build (layer-invariant) ----------------
template <int DT>
__device__ void ellb_body(const void* adj00, const void* b01, const void* adj11,
                          const void* b12, const void* adj22,
                          const void* b01T, const void* b12T, int tpok,
                          const int* bel0, const int* bel1, const int* bel2,
                          const int* ranges, int* ell, int* nnz) {
  const int sdv[7] = {0, 0, 1, 1, 1, 2, 2};
  const int tdv[7] = {0, 1, 0, 1, 2, 1, 2};
  int bi = blockIdx.x;
  int i, t;
  ct67_itab(bi, i, t);
  int lane = threadIdx.x;
  const void* mp; long mts, mss;
  switch (i) {
    case 0: mp = adj00; mts = 1536; mss = 1; break;
    case 1: if (tpok) { mp = b01T; mts = 1536; mss = 1; }
            else      { mp = b01;  mts = 1;    mss = 3072; } break;
    case 2: mp = b01; mts = 3072; mss = 1; break;
    case 3: mp = adj11; mts = 3072; mss = 1; break;
    case 4: if (tpok) { mp = b12T; mts = 3072; mss = 1; }
            else      { mp = b12;  mts = 1;    mss = 1536; } break;
    case 5: mp = b12; mts = 1536; mss = 1; break;
    default: mp = adj22; mts = 1536; mss = 1; break;
  }
  const int* belt = (tdv[i] == 0) ? bel0 : ((tdv[i] == 1) ? bel1 : bel2);
  int b = belt[t];
  if (b < 0) b = 0;
  if (b > 7) b = 7;
  const int* rng = ranges + sdv[i] * 16;
  int s0 = rng[b * 2], s1 = rng[b * 2 + 1];
  int base = 0;
  for (int s = s0; s < s1; s += 64) {
    int ss = s + lane;
    bool pred = false;
    if (ss < s1) pred = msknzT<DT>(mp, (long)t * mts + (long)ss * mss);
    unsigned long long bal = __ballot(pred);
    int pos = __popcll(bal & ((1ull << lane) - 1ull));
    if (pred && base + pos < 128) ell[(long)bi * 128 + base + pos] = ss;
    base += __popcll(bal);
  }
  if (lane == 0) nnz[bi] = base;
}
__global__ void ct67_ellb(const void* adj00, const void* b01, const void* adj11,
                          const void* b12, const void* adj22,
                          const void* b01T, const void* b12T, int tpok,
                          const int* bel0, const int* bel1, const int* bel2,
                          const int* ranges, int* ell, int* nnz, const int* dtp) {
  int dt = dtp[0];
  if (dt == 0)
    ellb_body<0>(adj00,b01,adj11,b12,adj22,b01T,b12T,tpok,bel0,bel1,bel2,ranges,ell,nnz);
  else if (dt == 1)
    ellb_body<1>(adj00,b01,adj11,b12,adj22,b01T,b12T,tpok,bel0,bel1,bel2,ranges,ell,nnz);
  else
    ellb_body<2>(adj00,b01,adj11,b12,adj22,b01T,b12T,tpok,bel0,bel1,bel2,ranges,ell,nnz);
}

// ---------------- embed (merged dims) ----------------
template <int DT>
__device__ void embed_body(const void* x0, const void* pe0, const void* wf0, const void* bf0,
                           const void* wp0, const void* x1, const void* pe1, const void* wf1,
                           const void* bf1, const void* wp1, const void* x2, const void* pe2,
                           const void* wf2, const void* bf2, const void* wp2, float* hout) {
  int j = threadIdx.x % 64;
  int row = blockIdx.x * 4 + threadIdx.x / 64;
  int d = (row < 1536) ? 0 : ((row < 4608) ? 1 : 2);
  int r = row - ((d == 0) ? 0 : ((d == 1) ? 1536 : 4608));
  const void* x  = (d == 0) ? x0  : ((d == 1) ? x1  : x2);
  const void* pe = (d == 0) ? pe0 : ((d == 1) ? pe1 : pe2);
  const void* wf = (d == 0) ? wf0 : ((d == 1) ? wf1 : wf2);
  const void* bf = (d == 0) ? bf0 : ((d == 1) ? bf1 : bf2);
  const void* wp = (d == 0) ? wp0 : ((d == 1) ? wp1 : wp2);
  float acc = ldT<DT>(bf, j);
#pragma unroll 8
  for (int f = 0; f < 32; f++) acc += ldT<DT>(x, (long)r * 32 + f) * ldT<DT>(wf, f * 64 + j);
#pragma unroll 8
  for (int p = 0; p < 16; p++) acc += ldT<DT>(pe, (long)r * 16 + p) * ldT<DT>(wp, p * 64 + j);
  hout[(long)row * 64 + j] = acc;
}
__global__ void ct67_embed(const void* x0, const void* pe0, const void* wf0, const void* bf0,
                           const void* wp0, const void* x1, const void* pe1, const void* wf1,
                           const void* bf1, const void* wp1, const void* x2, const void* pe2,
                           const void* wf2, const void* bf2, const void* wp2, float* hout,
                           const int* dtp) {
  int dt = dtp[0];
  if (dt == 0)      embed_body<0>(x0,pe0,wf0,bf0,wp0,x1,pe1,wf1,bf1,wp1,x2,pe2,wf2,bf2,wp2,hout);
  else if (dt == 1) embed_body<1>(x0,pe0,wf0,bf0,wp0,x1,pe1,wf1,bf1,wp1,x2,pe2,wf2,bf2,wp2,hout);
  else              embed_body<2>(x0,pe0,wf0,bf0,wp0,x1,pe1,wf1,bf1,wp1,x2,pe2,wf2,bf2,wp2,hout);
}

// ---------------- qkv: 8 rows/block, W decoded once into f32 LDS ----------------
template <int DT>
__device__ void qkv_body(const float* h, const void* Wq, const void* bq, const void* Wk,
                         const void* bk, const void* Wv, const void* bv,
                         float* qd, float* kd, float* vd, int l) {
  const int segend[21] = {1536, 3072, 4608, 7680, 9216, 10752, 12288, 15360, 18432,
                          21504, 24576, 27648, 29184, 32256, 35328, 38400, 39936,
                          41472, 43008, 44544, 46080};
  const int segsrc[21] = {0, 0, 0, 1, 0, 0, 0, 1, 1, 1, 1, 1, 2, 1, 1, 1, 2, 2, 2, 2, 2};
  const int segdst[21] = {0, 0, 0, 1536, 1536, 1536, 4608, 3072, 3072, 6144, 6144, 6144,
                          9216, 9216, 9216, 10752, 12288, 12288, 13824, 13824, 13824};
  const int rowoff[3] = {0, 1536, 4608};
  __shared__ float sW[4096];
  __shared__ float sh[8][64];
  int tid = threadIdx.x;
  int j = tid % 64;
  int rg = tid / 64;
  int gbase = blockIdx.x * 8;  // segment boundaries are multiples of 8
  int seg = 0;
  while (gbase >= segend[seg]) seg++;
  int segstart = (seg == 0) ? 0 : segend[seg - 1];
  int i = seg / 3, role = seg - i * 3;
  const void* W = (role == 0) ? Wq : (role == 1) ? Wk : Wv;
  const void* bb = (role == 0) ? bq : (role == 1) ? bk : bv;
  long wbase = (long)(l * 7 + i) * 4096;
#pragma unroll
  for (int kkk = 0; kkk < 8; kkk++) {
    int idx = tid + kkk * 512;
    sW[idx] = ldT<DT>(W, wbase + idx);
  }
  int r = gbase - segstart + rg;
  int hrow = rowoff[segsrc[seg]] + r;
  sh[rg][j] = h[(long)hrow * 64 + j];
  __syncthreads();
  float acc = ldT<DT>(bb, (long)(l * 7 + i) * 64 + j);
#pragma unroll 8
  for (int kk = 0; kk < 64; kk++) acc += sh[rg][kk] * sW[kk * 64 + j];
  float* dst = ((role == 0) ? qd : (role == 1) ? kd : vd) + (long)(segdst[seg] + r) * 64;
  dst[j] = acc;
}
__global__ void ct67_qkv(const float* h, const void* Wq, const void* bq, const void* Wk,
                         const void* bk, const void* Wv, const void* bv,
                         float* qd, float* kd, float* vd, int l, const int* dtp) {
  int dt = dtp[0];
  if (dt == 0)      qkv_body<0>(h, Wq, bq, Wk, bk, Wv, bv, qd, kd, vd, l);
  else if (dt == 1) qkv_body<1>(h, Wq, bq, Wk, bk, Wv, bv, qd, kd, vd, l);
  else              qkv_body<2>(h, Wq, bq, Wk, bk, Wv, bv, qd, kd, vd, l);
}

// ---------------- fused masked attention + output projection (ELL hit lists) ----
template <int DT>
__device__ void attn_body(const float* qb, const float* kb, const float* vb,
                          const void* Wo, const void* bo,
                          const void* adj00, const void* b01, const void* adj11,
                          const void* b12, const void* adj22,
                          const int* bel0, const int* bel1, const int* bel2,
                          const int* ranges, const int* ell, const int* nnz, int ellok,
                          float* obuf, int l) {
  const int koff[7] = {0, 1536, 3072, 6144, 9216, 12288, 13824};
  const int sdv[7] = {0, 0, 1, 1, 1, 2, 2};
  const int tdv[7] = {0, 1, 0, 1, 2, 1, 2};
  __shared__ float sm[64], sl[64], so8[64][9], sO[64];
  int bi = blockIdx.x;
  int i, t;
  ct67_itab(bi, i, t);
  int lane = threadIdx.x;
  int hh = lane / 8, jj = lane % 8;
  const float4* qp = (const float4*)(qb + (long)bi * 64 + hh * 8);
  float4 q0 = qp[0], q1 = qp[1];
  const float* kbase = kb + (long)koff[i] * 64 + hh * 8;
  const float* vbase = vb + (long)koff[i] * 64 + hh * 8;
  float mr = -1e30f, lr = 0.f, o[8];
  for (int d = 0; d < 8; d++) o[d] = 0.f;
  int n = ellok ? nnz[bi] : 129;
  if (n <= 128) {
    const int* hl = ell + (long)bi * 128;
    for (int hidx = jj; hidx < n; hidx += 8) {
      int s = hl[hidx];
      const float4* kp = (const float4*)(kbase + (long)s * 64);
      float4 k0 = kp[0], k1 = kp[1];
      float sc = q0.x * k0.x + q0.y * k0.y + q0.z * k0.z + q0.w * k0.w +
                 q1.x * k1.x + q1.y * k1.y + q1.z * k1.z + q1.w * k1.w;
      sc *= 0.35355339059327373f;
      float nm = fmaxf(mr, sc);
      float fo = expf(mr - nm);
      float wv = expf(sc - nm);
      lr = lr * fo + wv;
      const float4* vp = (const float4*)(vbase + (long)s * 64);
      float4 v0 = vp[0], v1 = vp[1];
      o[0] = o[0] * fo + wv * v0.x; o[1] = o[1] * fo + wv * v0.y;
      o[2] = o[2] * fo + wv * v0.z; o[3] = o[3] * fo + wv * v0.w;
      o[4] = o[4] * fo + wv * v1.x; o[5] = o[5] * fo + wv * v1.y;
      o[6] = o[6] * fo + wv * v1.z; o[7] = o[7] * fo + wv * v1.w;
      mr = nm;
    }
  } else {  // fallback: in-loop mask scan
    const void* mp; long mts, mss;
    switch (i) {
      case 0: mp = adj00; mts = 1536; mss = 1; break;
      case 1: mp = b01;   mts = 1;    mss = 3072; break;
      case 2: mp = b01;   mts = 3072; mss = 1; break;
      case 3: mp = adj11; mts = 3072; mss = 1; break;
      case 4: mp = b12;   mts = 1;    mss = 1536; break;
      case 5: mp = b12;   mts = 1536; mss = 1; break;
      default: mp = adj22; mts = 1536; mss = 1; break;
    }
    const int* belt = (tdv[i] == 0) ? bel0 : ((tdv[i] == 1) ? bel1 : bel2);
    int b = belt[t];
    if (b < 0) b = 0;
    if (b > 7) b = 7;
    const int* rng = ranges + sdv[i] * 16;
    int s0 = rng[b * 2], s1 = rng[b * 2 + 1];
    for (int s = s0 + jj; s < s1; s += 8) {
      if (msknzT<DT>(mp, (long)t * mts + (long)s * mss)) {
        const float4* kp = (const float4*)(kbase + (long)s * 64);
        float4 k0 = kp[0], k1 = kp[1];
        float sc = q0.x * k0.x + q0.y * k0.y + q0.z * k0.z + q0.w * k0.w +
                   q1.x * k1.x + q1.y * k1.y + q1.z * k1.z + q1.w * k1.w;
        sc *= 0.35355339059327373f;
        float nm = fmaxf(mr, sc);
        float fo = expf(mr - nm);
        float wv = expf(sc - nm);
        lr = lr * fo + wv;
        const float4* vp = (const float4*)(vbase + (long)s * 64);
        float4 v0 = vp[0], v1 = vp[1];
        o[0] = o[0] * fo + wv * v0.x; o[1] = o[1] * fo + wv * v0.y;
        o[2] = o[2] * fo + wv * v0.z; o[3] = o[3] * fo + wv * v0.w;
        o[4] = o[4] * fo + wv * v1.x; o[5] = o[5] * fo + wv * v1.y;
        o[6] = o[6] * fo + wv * v1.z; o[7] = o[7] * fo + wv * v1.w;
        mr = nm;
      }
    }
  }
  sm[lane] = mr;
  sl[lane] = lr;
  for (int d = 0; d < 8; d++) so8[lane][d] = o[d];
  __syncthreads();
  if (jj == 0) {
    float M = -1e30f, L = 0.f, O[8];
    for (int d = 0; d < 8; d++) O[d] = 0.f;
    for (int p = 0; p < 8; p++) {
      int src = hh * 8 + p;
      float m2 = sm[src], l2 = sl[src];
      float nm = fmaxf(M, m2);
      float f1 = expf(M - nm), f2 = expf(m2 - nm);
      L = L * f1 + l2 * f2;
      for (int d = 0; d < 8; d++) O[d] = O[d] * f1 + so8[src][d] * f2;
      M = nm;
    }
    for (int d = 0; d < 8; d++) sO[hh * 8 + d] = (L > 0.f) ? (O[d] / L) : 0.f;
  }
  __syncthreads();
  long wobase = (long)(l * 7 + i) * 4096;
  float acc = ldT<DT>(bo, (long)(l * 7 + i) * 64 + lane);
#pragma unroll 8
  for (int kk = 0; kk < 64; kk++) acc += sO[kk] * ldT<DT>(Wo, wobase + kk * 64 + lane);
  obuf[(long)bi * 64 + lane] = acc;
}
__global__ void CellularTransformer_67345087201410_kernel(
    const float* qb, const float* kb, const float* vb, const void* Wo, const void* bo,
    const void* adj00, const void* b01, const void* adj11, const void* b12,
    const void* adj22, const int* bel0, const int* bel1, const int* bel2,
    const int* ranges, const int* ell, const int* nnz, int ellok,
    float* obuf, int l, const int* dtp) {
  int dt = dtp[0];
  if (dt == 0)
    attn_body<0>(qb,kb,vb,Wo,bo,adj00,b01,adj11,b12,adj22,bel0,bel1,bel2,ranges,ell,nnz,ellok,obuf,l);
  else if (dt == 1)
    attn_body<1>(qb,kb,vb,Wo,bo,adj00,b01,adj11,b12,adj22,bel0,bel1,bel2,ranges,ell,nnz,ellok,obuf,l);
  else
    attn_body<2>(qb,kb,vb,Wo,bo,adj00,b01,adj11,b12,adj22,bel0,bel1,bel2,ranges,ell,nnz,ellok,obuf,l);
}

// ---------------- fused FFN: LN1 -> FF1(relu) -> FF2 -> LN2, all in LDS ----------
template <int DT>
__device__ void ffn_body(const float* h, const float* obuf, float* hout,
                         const void* W1, const void* b1, const void* W2, const void* b2,
                         const void* g1, const void* be1, const void* g2, const void* be2,
                         int l) {
  __shared__ float sh[64];     // hn (LN1 output)
  __shared__ float sf[256];    // relu(hn@W1+b1)
  __shared__ float sp[4][64];  // ff2 partials
  int row = blockIdx.x;
  int tid = threadIdx.x;
  int d = (row < 1536) ? 0 : ((row < 4608) ? 1 : 2);
  long gb = (long)(l * 3 + d) * 64;
  // Phase A: wave 0 computes LN1(h + attn outputs)
  if (tid < 64) {
    int j = tid;
    long idx = (long)row * 64 + j;
    float x = h[idx];
    if (d == 0) {
      int r = row;
      x += obuf[(long)r * 64 + j] + obuf[(long)(4608 + r) * 64 + j];
    } else if (d == 1) {
      int r = row - 1536;
      x += obuf[(long)(1536 + r) * 64 + j] + obuf[(long)(6144 + r) * 64 + j] +
           obuf[(long)(10752 + r) * 64 + j];
    } else {
      int r = row - 4608;
      x += obuf[(long)(9216 + r) * 64 + j] + obuf[(long)(13824 + r) * 64 + j];
    }
    float mu = wred64(x) * 0.015625f;
    float dx = x - mu;
    float var = wred64(dx * dx) * 0.015625f;
    sh[j] = dx * rsqrtf(var + 1e-5f) * ldT<DT>(g1, gb + j) + ldT<DT>(be1, gb + j);
  }
  __syncthreads();
  // Phase B: 256 threads compute ff cols
  long wb1 = (long)(l * 3 + d) * 16384;
  float acc = ldT<DT>(b1, (long)(l * 3 + d) * 256 + tid);
#pragma unroll 8
  for (int kk = 0; kk < 64; kk++) acc += sh[kk] * ldT<DT>(W1, wb1 + kk * 256 + tid);
  sf[tid] = fmaxf(acc, 0.f);
  __syncthreads();
  // Phase C: ff @ W2 with 4 k-partials per output col
  int p = tid >> 6, j = tid & 63;
  long wb2 = (long)(l * 3 + d) * 16384;
  float a2 = 0.f;
  int k0 = p * 64;
#pragma unroll 8
  for (int kk = 0; kk < 64; kk++) a2 += sf[k0 + kk] * ldT<DT>(W2, wb2 + (long)(k0 + kk) * 64 + j);
  sp[p][j] = a2;
  __syncthreads();
  // Phase D: wave 0 reduces partials, adds residual, LN2, writes h
  if (tid < 64) {
    float x = sh[tid] + ldT<DT>(b2, gb + tid) +
              sp[0][tid] + sp[1][tid] + sp[2][tid] + sp[3][tid];
    float mu = wred64(x) * 0.015625f;
    float dx = x - mu;
    float var = wred64(dx * dx) * 0.015625f;
    hout[(long)row * 64 + tid] =
        dx * rsqrtf(var + 1e-5f) * ldT<DT>(g2, gb + tid) + ldT<DT>(be2, gb + tid);
  }
}
__global__ void ct67_ffn(const float* h, const float* obuf, float* hout,
                         const void* W1, const void* b1, const void* W2, const void* b2,
                         const void* g1, const void* be1, const void* g2, const void* be2,
                         int l, const int* dtp) {
  int dt = dtp[0];
  if (dt == 0)      ffn_body<0>(h, obuf, hout, W1, b1, W2, b2, g1, be1, g2, be2, l);
  else if (dt == 1) ffn_body<1>(h, obuf, hout, W1, b1, W2, b2, g1, be1, g2, be2, l);
  else              ffn_body<2>(h, obuf, hout, W1, b1, W2, b2, g1, be1, g2, be2, l);
}

// ---------------- pooling: two-stage (256 blocks, then 8) ----------------
__global__ void ct67_poolp(const float* h, const int* ranges, float* ppart) {
  int b = blockIdx.x;
  int c = blockIdx.y;
  int j = threadIdx.x;
  float s = 0.f;
  for (int d = 0; d < 3; d++) {
    int st = ranges[(d * 8 + b) * 2], en = ranges[(d * 8 + b) * 2 + 1];
    int ro = (d == 0) ? 0 : ((d == 1) ? 1536 : 4608);
    for (int r = st + c; r < en; r += 32) s += h[(long)(ro + r) * 64 + j];
  }
  ppart[(long)(b * 32 + c) * 64 + j] = s;
}
__global__ void ct67_poolf(const float* ppart, const int* ranges, float* pooled) {
  int b = blockIdx.x;
  int j = threadIdx.x;
  float s = 0.f;
  for (int c = 0; c < 32; c++) s += ppart[(long)(b * 32 + c) * 64 + j];
  int cnt = 0;
  for (int d = 0; d < 3; d++)
    cnt += ranges[(d * 8 + b) * 2 + 1] - ranges[(d * 8 + b) * 2];
  pooled[b * 64 + j] = (cnt > 0) ? (s / (float)cnt) : 0.f;
}

// ---------------- head MLP ----------------
template <int DT>
__device__ void mlp_body(const float* pooled, const void* Wh1, const void* bh1,
                         const void* Wh2, const void* bh2, const void* Wh3,
                         const void* bh3, float* out) {
  __shared__ float y1[8][64];
  __shared__ float y2[8][64];
  int tid = threadIdx.x;
  int b = tid / 64, j = tid % 64;
  float acc = ldT<DT>(bh1, j);
  for (int kk = 0; kk < 64; kk++) acc += pooled[b * 64 + kk] * ldT<DT>(Wh1, kk * 64 + j);
  y1[b][j] = fmaxf(acc, 0.f);
  __syncthreads();
  acc = ldT<DT>(bh2, j);
  for (int kk = 0; kk < 64; kk++) acc += y1[b][kk] * ldT<DT>(Wh2, kk * 64 + j);
  y2[b][j] = fmaxf(acc, 0.f);
  __syncthreads();
  if (j < 10) {
    float o = ldT<DT>(bh3, j);
    for (int kk = 0; kk < 64; kk++) o += y2[b][kk] * ldT<DT>(Wh3, kk * 10 + j);
    out[b * 10 + j] = o;
  }
}
__global__ void ct67_mlp(const float* pooled, const void* Wh1, const void* bh1,
                         const void* Wh2, const void* bh2, const void* Wh3,
                         const void* bh3, float* out, const int* dtp) {
  int dt = dtp[0];
  if (dt == 0)      mlp_body<0>(pooled, Wh1, bh1, Wh2, bh2, Wh3, bh3, out);
  else if (dt == 1) mlp_body<1>(pooled, Wh1, bh1, Wh2, bh2, Wh3, bh3, out);
  else              mlp_body<2>(pooled, Wh1, bh1, Wh2, bh2, Wh3, bh3, out);
}

extern "C" void kernel_launch(void* const* d_in, const int* in_sizes, int n_in,
                              void* d_out, int out_size, void* d_ws, size_t ws_size,
                              hipStream_t stream) {
  (void)in_sizes; (void)n_in; (void)out_size;
  const void* x0 = d_in[0];  const void* pe0 = d_in[1];  const int* bel0 = (const int*)d_in[2];
  const void* x1 = d_in[3];  const void* pe1 = d_in[4];  const int* bel1 = (const int*)d_in[5];
  const void* x2 = d_in[6];  const void* pe2 = d_in[7];  const int* bel2 = (const int*)d_in[8];
  const void* adj00 = d_in[9];  const void* adj11 = d_in[10]; const void* adj22 = d_in[11];
  const void* b01 = d_in[12];   const void* b12 = d_in[13];
  const void* Wf0 = d_in[14]; const void* bf0 = d_in[15]; const void* Wp0 = d_in[16];
  const void* Wf1 = d_in[17]; const void* bf1 = d_in[18]; const void* Wp1 = d_in[19];
  const void* Wf2 = d_in[20]; const void* bf2 = d_in[21]; const void* Wp2 = d_in[22];
  const void* Wq = d_in[23]; const void* bq = d_in[24];
  const void* Wk = d_in[25]; const void* bk = d_in[26];
  const void* Wv = d_in[27]; const void* bv = d_in[28];
  const void* Wo = d_in[29]; const void* bo = d_in[30];
  const void* g1 = d_in[31]; const void* be1 = d_in[32];
  const void* g2 = d_in[33]; const void* be2 = d_in[34];
  const void* Wff1 = d_in[35]; const void* bff1 = d_in[36];
  const void* Wff2 = d_in[37]; const void* bff2 = d_in[38];
  const void* Wh1 = d_in[39]; const void* bh1 = d_in[40];
  const void* Wh2 = d_in[41]; const void* bh2 = d_in[42];
  const void* Wh3 = d_in[43]; const void* bh3 = d_in[44];

  char* w = (char*)d_ws;
  float* hbuf   = (float*)(w + 0);          // 6144*64*4   = 1572864
  float* obuf   = (float*)(w + 1572864);    // 15360*64*4  = 3932160 -> 5505024
  float* qb     = (float*)(w + 5505024);    // -> 9437184
  float* kb     = (float*)(w + 9437184);    // -> 13369344
  float* vb     = (float*)(w + 13369344);   // -> 17301504
  float* pooled = (float*)(w + 17301504);   // 2048        -> 17303552
  int* ranges   = (int*)(w + 17303552);     // 192         -> 17303744
  int* flags    = (int*)(w + 17303744);     // 64          -> 17303808
  float* ppart  = (float*)(w + 17303808);   // 8*32*64*4   -> 17369344
  int* ell      = (int*)(w + 17369344);     // 15360*128*4 -> 25233664
  int* nnz      = (int*)(w + 25233664);     // 61440       -> 25295104
  void* b01T    = (void*)(w + 25295104);    // 3072*1536*4 -> 44169472
  void* b12T    = (void*)(w + 44169472);    // -> 63043840
  int ellok = (ws_size >= (size_t)25295104) ? 1 : 0;
  int tpok  = (ws_size >= (size_t)63043840) ? 1 : 0;

  ct67_init<<<1, 64, 0, stream>>>((const unsigned short*)x0, bel0, bel1, bel2, ranges, flags);
  if (tpok)
    ct67_tpose<<<9216, 256, 0, stream>>>(b01, b12, b01T, b12T, flags);
  if (ellok)
    ct67_ellb<<<15360, 64, 0, stream>>>(adj00, b01, adj11, b12, adj22, b01T, b12T, tpok,
                                        bel0, bel1, bel2, ranges, ell, nnz, flags);
  ct67_embed<<<1536, 256, 0, stream>>>(x0, pe0, Wf0, bf0, Wp0, x1, pe1, Wf1, bf1, Wp1,
                                       x2, pe2, Wf2, bf2, Wp2, hbuf, flags);
  for (int l = 0; l < 2; l++) {
    ct67_qkv<<<5760, 512, 0, stream>>>(hbuf, Wq, bq, Wk, bk, Wv, bv, qb, kb, vb, l, flags);
    CellularTransformer_67345087201410_kernel<<<15360, 64, 0, stream>>>(
        qb, kb, vb, Wo, bo, adj00, b01, adj11, b12, adj22,
        bel0, bel1, bel2, ranges, ell, nnz, ellok, obuf, l, flags);
    ct67_ffn<<<6144, 256, 0, stream>>>(hbuf, obuf, hbuf, Wff1, bff1, Wff2, bff2,
                                       g1, be1, g2, be2, l, flags);
  }
  ct67_poolp<<<dim3(8, 32), 64, 0, stream>>>(hbuf, ranges, ppart);
  ct67_poolf<<<8, 64, 0, stream>>>(ppart, ranges, pooled);
  ct67_mlp<<<1, 512, 0, stream>>>(pooled, Wh1, bh1, Wh2, bh2, Wh3, bh3, (float*)d_out, flags);
}